// Round 8
// baseline (444.103 us; speedup 1.0000x reference)
//
#include <hip/hip_runtime.h>
#include <math.h>

#define NB 8192
#define S_ 45
#define D_ 64
#define FF_ 256
#define LDH 68     // f32 row stride hf/t1
#define HBS 72     // bf16 row stride hb/ob/qb/kb
#define VTS 52     // bf16 row stride vT [64][52]
#define PS  52     // bf16 row stride P  [48][52] per head
#define FBS 280    // bf16 row stride FFN inner tile

typedef __attribute__((ext_vector_type(4))) float f32x4;
typedef __attribute__((ext_vector_type(8))) short s16x8;
typedef __attribute__((ext_vector_type(4))) short s16x4;

// ws layout (bytes): pe f32 [45*64] @0 ; WqkvT bf16 [192][64] @11520 ;
// WoT bf16 [64][64] @36096 ; W1T bf16 [256][64] @44288 ; W2T bf16 [64][256] @77056
#define WS_QKV 11520
#define WS_WO  36096
#define WS_W1  44288
#define WS_W2  77056

__device__ inline short f2bf(float f) {   // RNE float->bf16 bits
    union { float f; unsigned u; } c; c.f = f;
    unsigned u = c.u;
    return (short)((u + 0x7FFFu + ((u >> 16) & 1u)) >> 16);
}

__global__ void prep_kernel(const float* __restrict__ Wq, const float* __restrict__ Wk,
                            const float* __restrict__ Wv, const float* __restrict__ Wo,
                            const float* __restrict__ W1, const float* __restrict__ W2,
                            void* __restrict__ ws) {
    float* pe   = (float*)ws;
    short* wqkv = (short*)((char*)ws + WS_QKV);
    short* wo   = (short*)((char*)ws + WS_WO);
    short* w1   = (short*)((char*)ws + WS_W1);
    short* w2   = (short*)((char*)ws + WS_W2);
    int i = blockIdx.x * 256 + threadIdx.x;
    if (i < S_ * D_) {                       // positional encoding (f32)
        int s = i / D_, d = i % D_;
        float div = expf(-logf(10000.0f) * (float)(d & ~1) / (float)D_);
        float ang = (float)s * div;
        pe[i] = (d & 1) ? cosf(ang) : sinf(ang);
    }
    if (i < 12288) {                         // WqkvT[n][k] = W{q,k,v}[k][n&63]
        int n = i >> 6, k = i & 63;
        const float* W = (n < 64) ? Wq : (n < 128 ? Wk : Wv);
        wqkv[i] = f2bf(W[k * 64 + (n & 63)]);
    }
    if (i < 4096) {                          // WoT[n][k] = Wo[k][n]
        int n = i >> 6, k = i & 63;
        wo[i] = f2bf(Wo[k * 64 + n]);
    }
    if (i < 16384) {
        int n = i >> 6, k = i & 63;          // W1T[n][k] = W1[k][n]
        w1[i] = f2bf(W1[k * FF_ + n]);
        int n2 = i >> 8, k2 = i & 255;       // W2T[n][k] = W2[k][n]
        w2[i] = f2bf(W2[k2 * 64 + n2]);
    }
}

__launch_bounds__(512, 1)
__global__ void encoder_kernel(
    const float* __restrict__ x,
    const float* __restrict__ bq, const float* __restrict__ bk,
    const float* __restrict__ bv, const float* __restrict__ bo,
    const float* __restrict__ ln1g, const float* __restrict__ ln1b,
    const float* __restrict__ b1, const float* __restrict__ b2,
    const float* __restrict__ ln2g, const float* __restrict__ ln2b,
    const void* __restrict__ ws,
    float* __restrict__ out)
{
    const float* pe    = (const float*)ws;
    const short* wqkvT = (const short*)((const char*)ws + WS_QKV);
    const short* woT   = (const short*)((const char*)ws + WS_WO);
    const short* w1T   = (const short*)((const char*)ws + WS_W1);
    const short* w2T   = (const short*)((const char*)ws + WS_W2);

    // LDS pool 79568 B -> 2 blocks/CU. Overlays (phase-disjoint):
    //  @0     hf   f32 [45][68] 12240B   residual h -> h2 -> t2   (persists)
    //  @12240 hb  bf16 [48][72]  6912B   h (QKV A-op) / ob (attn out) / h2 (FFN1 A-op)
    //  @19152 qb  bf16 [48][72]  6912B   q' scaled        | t1 f32 [45][68] (Wo out)
    //  @26064 kb  bf16 [48][72]  6912B   k                |   (t1 spans qb+kb)
    //  @32976 vT  bf16 [64][52]  6656B   v transposed [d][kr]
    //  @39632 Pb  bf16 [8][48][52] 39936B  softmax probs  | fb bf16 [48][280] (FFN)
    __shared__ __align__(16) char pool[79568];
    float* hf = (float*)pool;
    short* hb = (short*)(pool + 12240);
    short* ob = hb;
    short* qb = (short*)(pool + 19152);
    short* kb = (short*)(pool + 26064);
    short* vT = (short*)(pool + 32976);
    short* Pb = (short*)(pool + 39632);
    float* t1 = (float*)(pool + 19152);
    short* fb = (short*)(pool + 39632);

    const int t = threadIdx.x;
    const int b = blockIdx.x;
    const int w = t >> 6, l = t & 63;
    const int lr = l & 15, lg = l >> 4;   // MFMA frag coords
    const s16x8 zero8 = {0, 0, 0, 0, 0, 0, 0, 0};

    // ---- 1. h = x + pe -> hf (f32) + hb (bf16); ZERO hb pad rows -------
    // hb rows 45..47 feed MFMA A-rows whose results reach vT's K-axis pads;
    // they must be true zeros (K-axis garbage => 0*NaN = NaN everywhere).
    {
        const float4* x4 = (const float4*)(x + (size_t)b * (S_ * D_));
        const float4* p4 = (const float4*)pe;
        for (int i = t; i < S_ * D_ / 4; i += 512) {
            int r = i >> 4, c4 = (i & 15) << 2;
            float4 a = x4[i], p = p4[i];
            float4 hv = make_float4(a.x + p.x, a.y + p.y, a.z + p.z, a.w + p.w);
            *(float4*)&hf[r * LDH + c4] = hv;
            s16x4 hv16 = { f2bf(hv.x), f2bf(hv.y), f2bf(hv.z), f2bf(hv.w) };
            *(s16x4*)&hb[r * HBS + c4] = hv16;
        }
        for (int i = t; i < 3 * HBS; i += 512) hb[45 * HBS + i] = 0;
    }
    __syncthreads();

    // ---- 2. fused QKV via MFMA -> qb (scaled q'), kb, vT (transposed) --
    // Writes are UNCONDITIONAL (rows 45..47 included): with hb pads zeroed
    // they hold clean bias values, keeping kb scores finite and vT pads 0.
    {
        const float SC2 = 0.35355339059327373f * 1.44269504088896340f; // 1/sqrt(8)*log2e
        for (int id = w; id < 36; id += 8) {
            const int m0 = (id % 3) << 4, n0 = (id / 3) << 4;
            f32x4 acc = {0.f, 0.f, 0.f, 0.f};
            #pragma unroll
            for (int k0 = 0; k0 < 64; k0 += 32) {
                s16x8 af = *(const s16x8*)&hb[(m0 + lr) * HBS + k0 + lg * 8];
                s16x8 bf = *(const s16x8*)&wqkvT[(n0 + lr) * 64 + k0 + lg * 8];
                acc = __builtin_amdgcn_mfma_f32_16x16x32_bf16(af, bf, acc, 0, 0, 0);
            }
            if (n0 < 64) {                       // q' = (q+bq)*SC2
                const float bias = bq[n0 + lr];
                #pragma unroll
                for (int r = 0; r < 4; ++r) {
                    int row = m0 + lg * 4 + r;
                    qb[row * HBS + n0 + lr] = f2bf((acc[r] + bias) * SC2);
                }
            } else if (n0 < 128) {               // k
                const int cc = n0 - 64 + lr;
                const float bias = bk[cc];
                #pragma unroll
                for (int r = 0; r < 4; ++r) {
                    int row = m0 + lg * 4 + r;
                    kb[row * HBS + cc] = f2bf(acc[r] + bias);
                }
            } else {                             // v -> vT[d][kr], packed 4 kr
                const int cc = n0 - 128 + lr;
                const float bias = bv[cc];
                s16x4 vv = { f2bf(acc[0] + bias), f2bf(acc[1] + bias),
                             f2bf(acc[2] + bias), f2bf(acc[3] + bias) };
                *(s16x4*)&vT[cc * VTS + m0 + lg * 4] = vv;
            }
        }
    }
    __syncthreads();

    // ---- 3. QK^T via MFMA (1 head/wave) + in-register softmax -> Pb ----
    {
        const int hd = w << 3;
        s16x8 af[3], bf[3];
        #pragma unroll
        for (int i = 0; i < 3; ++i) {   // K=8 zero-padded to 32: lg==0 carries data
            af[i] = (lg == 0) ? *(const s16x8*)&qb[(i * 16 + lr) * HBS + hd] : zero8;
            bf[i] = (lg == 0) ? *(const s16x8*)&kb[(i * 16 + lr) * HBS + hd] : zero8;
        }
        f32x4 S[3][3];
        #pragma unroll
        for (int tm = 0; tm < 3; ++tm)
            #pragma unroll
            for (int tn = 0; tn < 3; ++tn) {
                f32x4 z = {0.f, 0.f, 0.f, 0.f};
                S[tm][tn] = __builtin_amdgcn_mfma_f32_16x16x32_bf16(af[tm], bf[tn], z, 0, 0, 0);
            }
        // softmax along kr (= lane lr axis + 3 tiles), normalize, store bf16
        #pragma unroll
        for (int tm = 0; tm < 3; ++tm) {
            #pragma unroll
            for (int r = 0; r < 4; ++r) {
                float p0 = __builtin_amdgcn_exp2f(S[tm][0][r]);
                float p1 = __builtin_amdgcn_exp2f(S[tm][1][r]);
                float p2 = __builtin_amdgcn_exp2f(S[tm][2][r]);
                p2 = (lr >= 13) ? 0.f : p2;            // kr = 32+lr >= 45 masked
                float s = p0 + p1 + p2;
                s += __shfl_xor(s, 1);  s += __shfl_xor(s, 2);
                s += __shfl_xor(s, 4);  s += __shfl_xor(s, 8);
                float inv = 1.0f / s;
                int rowbase = (w * 48 + tm * 16 + lg * 4 + r) * PS;
                Pb[rowbase + lr]      = f2bf(p0 * inv);
                Pb[rowbase + 16 + lr] = f2bf(p1 * inv);
                Pb[rowbase + 32 + lr] = f2bf(p2 * inv);
            }
        }
    }
    __syncthreads();

    // ---- 4. PV via MFMA (1 head/wave): o = P @ vT^T -> ob (bf16) -------
    {
        const int hd = w << 3;
        // B-frags from vT rows hd+lr (cols 8..15 feed discarded output cols)
        s16x8 bfa = *(const s16x8*)&vT[(hd + lr) * VTS + lg * 8];            // kr 0..31
        s16x8 bfb = (lg < 2) ? *(const s16x8*)&vT[(hd + lr) * VTS + 32 + lg * 8]
                             : zero8;                                        // kr 32..47
        f32x4 O[3];
        #pragma unroll
        for (int tm = 0; tm < 3; ++tm) {
            const int rowbase = (w * 48 + tm * 16 + lr) * PS;
            s16x8 afa = *(const s16x8*)&Pb[rowbase + lg * 8];
            s16x8 afb = (lg < 2) ? *(const s16x8*)&Pb[rowbase + 32 + lg * 8] : zero8;
            f32x4 z = {0.f, 0.f, 0.f, 0.f};
            O[tm] = __builtin_amdgcn_mfma_f32_16x16x32_bf16(afa, bfa, z, 0, 0, 0);
            O[tm] = __builtin_amdgcn_mfma_f32_16x16x32_bf16(afb, bfb, O[tm], 0, 0, 0);
        }
        if (lr < 8) {                        // valid d cols only
            #pragma unroll
            for (int tm = 0; tm < 3; ++tm)
                #pragma unroll
                for (int r = 0; r < 4; ++r) {
                    int row = tm * 16 + lg * 4 + r;
                    if (row < S_) ob[row * HBS + hd + lr] = f2bf(O[tm][r]);
                }
        }
    }
    __syncthreads();

    // ---- 5. t1 = o @ Wo + bo + h (residual), MFMA -> t1 (f32) ----------
    {
        for (int id = w; id < 12; id += 8) {
            const int m0 = (id % 3) << 4, n0 = (id / 3) << 4;
            f32x4 acc = {0.f, 0.f, 0.f, 0.f};
            #pragma unroll
            for (int k0 = 0; k0 < 64; k0 += 32) {
                s16x8 af = *(const s16x8*)&ob[(m0 + lr) * HBS + k0 + lg * 8];
                s16x8 bf = *(const s16x8*)&woT[(n0 + lr) * 64 + k0 + lg * 8];
                acc = __builtin_amdgcn_mfma_f32_16x16x32_bf16(af, bf, acc, 0, 0, 0);
            }
            const int col = n0 + lr;
            const float bias = bo[col];
            #pragma unroll
            for (int r = 0; r < 4; ++r) {
                int row = m0 + lg * 4 + r;
                if (row < S_)
                    t1[row * LDH + col] = acc[r] + bias + hf[row * LDH + col];
            }
        }
    }
    __syncthreads();

    // ---- 6. LN1: t1 -> h2 (hf f32 + hb bf16) ---------------------------
    {
        const int wv = t >> 6, d = t & 63;
        const float g = ln1g[d], bb = ln1b[d];
        for (int i = 0; i < 6; ++i) {
            int r = wv + 8 * i;
            if (r < S_) {
                float v = t1[r * LDH + d];
                float s = v, s2 = v * v;
                #pragma unroll
                for (int off = 32; off; off >>= 1) {
                    s  += __shfl_xor(s, off);
                    s2 += __shfl_xor(s2, off);
                }
                float mean = s * (1.0f / 64.0f);
                float var  = s2 * (1.0f / 64.0f) - mean * mean;
                float nv = (v - mean) * rsqrtf(var + 1e-5f);
                float res = nv * g + bb;
                hf[r * LDH + d] = res;
                hb[r * HBS + d] = f2bf(res);
            }
        }
    }
    __syncthreads();

    // ---- 7. FFN1 via MFMA: f = relu(h2 @ W1 + b1) -> fb (bf16) ---------
    {
        for (int id = w; id < 48; id += 8) {
            const int m0 = (id % 3) << 4, n0 = (id / 3) << 4;
            f32x4 acc = {0.f, 0.f, 0.f, 0.f};
            #pragma unroll
            for (int k0 = 0; k0 < 64; k0 += 32) {
                s16x8 af = *(const s16x8*)&hb[(m0 + lr) * HBS + k0 + lg * 8];
                s16x8 bf = *(const s16x8*)&w1T[(n0 + lr) * 64 + k0 + lg * 8];
                acc = __builtin_amdgcn_mfma_f32_16x16x32_bf16(af, bf, acc, 0, 0, 0);
            }
            const int col = n0 + lr;
            const float bias = b1[col];
            #pragma unroll
            for (int r = 0; r < 4; ++r) {
                int row = m0 + lg * 4 + r;
                if (row < S_)
                    fb[row * FBS + col] = f2bf(fmaxf(acc[r] + bias, 0.f));
            }
        }
    }
    __syncthreads();

    // ---- 8. FFN2 via MFMA: t2 = f @ W2 + b2 + h2 -> hf (in place) ------
    {
        for (int id = w; id < 12; id += 8) {
            const int m0 = (id % 3) << 4, n0 = (id / 3) << 4;
            f32x4 acc = {0.f, 0.f, 0.f, 0.f};
            #pragma unroll 4
            for (int k0 = 0; k0 < FF_; k0 += 32) {
                s16x8 af = *(const s16x8*)&fb[(m0 + lr) * FBS + k0 + lg * 8];
                s16x8 bf = *(const s16x8*)&w2T[(n0 + lr) * 256 + k0 + lg * 8];
                acc = __builtin_amdgcn_mfma_f32_16x16x32_bf16(af, bf, acc, 0, 0, 0);
            }
            const int col = n0 + lr;
            const float bias = b2[col];
            #pragma unroll
            for (int r = 0; r < 4; ++r) {
                int row = m0 + lg * 4 + r;
                if (row < S_) {
                    int o = row * LDH + col;
                    hf[o] = acc[r] + bias + hf[o];
                }
            }
        }
    }
    __syncthreads();

    // ---- 9. LN2: hf -> out ---------------------------------------------
    {
        const int wv = t >> 6, d = t & 63;
        const float g = ln2g[d], bb = ln2b[d];
        for (int i = 0; i < 6; ++i) {
            int r = wv + 8 * i;
            if (r < S_) {
                float v = hf[r * LDH + d];
                float s = v, s2 = v * v;
                #pragma unroll
                for (int off = 32; off; off >>= 1) {
                    s  += __shfl_xor(s, off);
                    s2 += __shfl_xor(s2, off);
                }
                float mean = s * (1.0f / 64.0f);
                float var  = s2 * (1.0f / 64.0f) - mean * mean;
                float nv = (v - mean) * rsqrtf(var + 1e-5f);
                out[(size_t)b * (S_ * D_) + r * 64 + d] = nv * g + bb;
            }
        }
    }
}

extern "C" void kernel_launch(void* const* d_in, const int* in_sizes, int n_in,
                              void* d_out, int out_size, void* d_ws, size_t ws_size,
                              hipStream_t stream) {
    const float* x    = (const float*)d_in[0];
    const float* Wq   = (const float*)d_in[1];
    const float* bq   = (const float*)d_in[2];
    const float* Wk   = (const float*)d_in[3];
    const float* bk   = (const float*)d_in[4];
    const float* Wv   = (const float*)d_in[5];
    const float* bv   = (const float*)d_in[6];
    const float* Wo   = (const float*)d_in[7];
    const float* bo   = (const float*)d_in[8];
    const float* ln1g = (const float*)d_in[9];
    const float* ln1b = (const float*)d_in[10];
    const float* W1   = (const float*)d_in[11];
    const float* b1   = (const float*)d_in[12];
    const float* W2   = (const float*)d_in[13];
    const float* b2   = (const float*)d_in[14];
    const float* ln2g = (const float*)d_in[15];
    const float* ln2b = (const float*)d_in[16];
    float* out = (float*)d_out;

    hipLaunchKernelGGL(prep_kernel, dim3(64), dim3(256), 0, stream,
                       Wq, Wk, Wv, Wo, W1, W2, d_ws);
    hipLaunchKernelGGL(encoder_kernel, dim3(NB), dim3(512), 0, stream,
                       x, bq, bk, bv, bo, ln1g, ln1b, b1, b2, ln2g, ln2b,
                       d_ws, out);
}

// Round 11
// 422.940 us; speedup vs baseline: 1.0500x; 1.0500x over previous
//
#include <hip/hip_runtime.h>
#include <math.h>

#define NB 8192
#define S_ 45
#define D_ 64
#define FF_ 256
#define LDH 68     // f32 row stride hf/t1
#define HBS 72     // 16-bit row stride hb/ob/qh/kh (144 B)
#define FBH 136    // bf16 row stride FFN half tile [48][136]

typedef __attribute__((ext_vector_type(4))) float f32x4;
typedef __attribute__((ext_vector_type(8))) short s16x8;
typedef __attribute__((ext_vector_type(4))) short s16x4;
typedef __fp16 h16x2 __attribute__((ext_vector_type(2)));

// ws layout (bytes): pe f32 [45*64] @0 ; WqkvT bf16 [192][64] @11520 ;
// WoT bf16 [64][64] @36096 ; W1T bf16 [256][64] @44288 ; W2T bf16 [64][256] @77056
#define WS_QKV 11520
#define WS_WO  36096
#define WS_W1  44288
#define WS_W2  77056

__device__ inline short f2bf(float f) {   // RNE float->bf16 bits
    union { float f; unsigned u; } c; c.f = f;
    unsigned u = c.u;
    return (short)((u + 0x7FFFu + ((u >> 16) & 1u)) >> 16);
}

__global__ void prep_kernel(const float* __restrict__ Wq, const float* __restrict__ Wk,
                            const float* __restrict__ Wv, const float* __restrict__ Wo,
                            const float* __restrict__ W1, const float* __restrict__ W2,
                            void* __restrict__ ws) {
    float* pe   = (float*)ws;
    short* wqkv = (short*)((char*)ws + WS_QKV);
    short* wo   = (short*)((char*)ws + WS_WO);
    short* w1   = (short*)((char*)ws + WS_W1);
    short* w2   = (short*)((char*)ws + WS_W2);
    int i = blockIdx.x * 256 + threadIdx.x;
    if (i < S_ * D_) {                       // positional encoding (f32)
        int s = i / D_, d = i % D_;
        float div = expf(-logf(10000.0f) * (float)(d & ~1) / (float)D_);
        float ang = (float)s * div;
        pe[i] = (d & 1) ? cosf(ang) : sinf(ang);
    }
    if (i < 12288) {                         // WqkvT[n][k] = W{q,k,v}[k][n&63]
        int n = i >> 6, k = i & 63;
        const float* W = (n < 64) ? Wq : (n < 128 ? Wk : Wv);
        wqkv[i] = f2bf(W[k * 64 + (n & 63)]);
    }
    if (i < 4096) {                          // WoT[n][k] = Wo[k][n]
        int n = i >> 6, k = i & 63;
        wo[i] = f2bf(Wo[k * 64 + n]);
    }
    if (i < 16384) {
        int n = i >> 6, k = i & 63;          // W1T[n][k] = W1[k][n]
        w1[i] = f2bf(W1[k * FF_ + n]);
        int n2 = i >> 8, k2 = i & 255;       // W2T[n][k] = W2[k][n]
        w2[i] = f2bf(W2[k2 * 64 + n2]);
    }
}

__launch_bounds__(512, 1)
__global__ void encoder_kernel(
    const float* __restrict__ x,
    const float* __restrict__ bq, const float* __restrict__ bk,
    const float* __restrict__ bv, const float* __restrict__ bo,
    const float* __restrict__ ln1g, const float* __restrict__ ln1b,
    const float* __restrict__ b1, const float* __restrict__ b2,
    const float* __restrict__ ln2g, const float* __restrict__ ln2b,
    const void* __restrict__ ws,
    float* __restrict__ out)
{
    const float* pe    = (const float*)ws;
    const short* wqkvT = (const short*)((const char*)ws + WS_QKV);
    const short* woT   = (const short*)((const char*)ws + WS_WO);
    const short* w1T   = (const short*)((const char*)ws + WS_W1);
    const short* w2T   = (const short*)((const char*)ws + WS_W2);

    // LDS pool 39120 B -> 4 blocks/CU. Overlays (phase-disjoint):
    //  @0     hf   f32 [45][68] 12240B   residual h -> h2 -> t2 (persists)
    //  @12240 hb  bf16 [48][72]  6912B   h (QKV A-op) / ob / h2 (FFN1 A-op)
    //  @19152 union (19968B):
    //    attn : qh f16 [48][72] | kh f16 [48][72] @+6912 | vh f16 [48][64] @+13824
    //    Wo   : t1 f32 [45][68] (12240B)
    //    FFN  : fb bf16 [48][136] half tile (13056B)
    __shared__ __align__(16) char pool[39120];
    float*   hf = (float*)pool;
    short*   hb = (short*)(pool + 12240);
    short*   ob = hb;
    __fp16*  qh = (__fp16*)(pool + 19152);
    __fp16*  kh = (__fp16*)(pool + 26064);
    __fp16*  vh = (__fp16*)(pool + 32976);    // [48][64] row-major (proven R6 form)
    float*   t1 = (float*)(pool + 19152);
    short*   fb = (short*)(pool + 19152);

    const int t = threadIdx.x;
    const int b = blockIdx.x;
    const int w = t >> 6, l = t & 63;
    const int lr = l & 15, lg = l >> 4;   // MFMA frag coords

    // ---- 1. h = x + pe -> hf (f32) + hb (bf16); zero hb pad rows -------
    {
        const float4* x4 = (const float4*)(x + (size_t)b * (S_ * D_));
        const float4* p4 = (const float4*)pe;
        for (int i = t; i < S_ * D_ / 4; i += 512) {
            int r = i >> 4, c4 = (i & 15) << 2;
            float4 a = x4[i], p = p4[i];
            float4 hv = make_float4(a.x + p.x, a.y + p.y, a.z + p.z, a.w + p.w);
            *(float4*)&hf[r * LDH + c4] = hv;
            s16x4 hv16 = { f2bf(hv.x), f2bf(hv.y), f2bf(hv.z), f2bf(hv.w) };
            *(s16x4*)&hb[r * HBS + c4] = hv16;
        }
        for (int i = t; i < 3 * HBS; i += 512) hb[45 * HBS + i] = 0;
    }
    __syncthreads();

    // ---- 2. fused QKV via MFMA -> qh (f16, scaled), kh (f16), vh (f16) -
    // Unconditional epilogues: pad rows come from zeroed hb -> finite bias.
    {
        const float SC2 = 0.35355339059327373f * 1.44269504088896340f; // 1/sqrt(8)*log2e
        for (int id = w; id < 36; id += 8) {
            const int m0 = (id % 3) << 4, n0 = (id / 3) << 4;
            f32x4 acc = {0.f, 0.f, 0.f, 0.f};
            #pragma unroll
            for (int k0 = 0; k0 < 64; k0 += 32) {
                s16x8 af = *(const s16x8*)&hb[(m0 + lr) * HBS + k0 + lg * 8];
                s16x8 bf = *(const s16x8*)&wqkvT[(n0 + lr) * 64 + k0 + lg * 8];
                acc = __builtin_amdgcn_mfma_f32_16x16x32_bf16(af, bf, acc, 0, 0, 0);
            }
            if (n0 < 64) {                       // q' = (q+bq)*SC2, f16
                const float bias = bq[n0 + lr];
                #pragma unroll
                for (int r = 0; r < 4; ++r)
                    qh[(m0 + lg * 4 + r) * HBS + n0 + lr] = (__fp16)((acc[r] + bias) * SC2);
            } else if (n0 < 128) {               // k, f16
                const int cc = n0 - 64 + lr;
                const float bias = bk[cc];
                #pragma unroll
                for (int r = 0; r < 4; ++r)
                    kh[(m0 + lg * 4 + r) * HBS + cc] = (__fp16)(acc[r] + bias);
            } else {                             // v, f16 row-major [48][64]
                const int cc = n0 - 128 + lr;
                const float bias = bv[cc];
                #pragma unroll
                for (int r = 0; r < 4; ++r)
                    vh[(m0 + lg * 4 + r) * 64 + cc] = (__fp16)(acc[r] + bias);
            }
        }
    }
    __syncthreads();

    // ---- 3. attention: explicit f32 math (proven R6 form), f16 inputs --
    {
        if (t < S_ * 8) {
            const int qr = t >> 3, hd = (t & 7) << 3;
            float qv[8];
            {
                const h16x2* qp = (const h16x2*)&qh[qr * HBS + hd];
                #pragma unroll
                for (int j = 0; j < 4; ++j) {
                    h16x2 qq = qp[j];
                    qv[2 * j]     = (float)qq.x;
                    qv[2 * j + 1] = (float)qq.y;
                }
            }
            float o[8];
            #pragma unroll
            for (int j = 0; j < 8; ++j) o[j] = 0.f;
            float lsum = 0.f;
            #pragma unroll 3
            for (int k = 0; k < S_; ++k) {
                const h16x2* kp_ = (const h16x2*)&kh[k * HBS + hd];
                float d = 0.f;
                #pragma unroll
                for (int j = 0; j < 4; ++j) {
                    h16x2 kk = kp_[j];
                    d += qv[2 * j] * (float)kk.x + qv[2 * j + 1] * (float)kk.y;
                }
                float p = __builtin_amdgcn_exp2f(d);   // scale folded into q'
                lsum += p;
                const h16x2* vr = (const h16x2*)&vh[k * 64 + hd];
                #pragma unroll
                for (int j = 0; j < 4; ++j) {
                    h16x2 vv = vr[j];
                    o[2 * j]     += p * (float)vv.x;
                    o[2 * j + 1] += p * (float)vv.y;
                }
            }
            float inv = 1.0f / lsum;
            s16x8 o16;
            #pragma unroll
            for (int j = 0; j < 8; ++j) o16[j] = f2bf(o[j] * inv);
            *(s16x8*)&ob[qr * HBS + hd] = o16;   // ob = hb region (h dead)
        }
    }
    __syncthreads();

    // ---- 4. t1 = o @ Wo + bo + h (residual), MFMA -> t1 (f32) ----------
    {
        for (int id = w; id < 12; id += 8) {
            const int m0 = (id % 3) << 4, n0 = (id / 3) << 4;
            f32x4 acc = {0.f, 0.f, 0.f, 0.f};
            #pragma unroll
            for (int k0 = 0; k0 < 64; k0 += 32) {
                s16x8 af = *(const s16x8*)&ob[(m0 + lr) * HBS + k0 + lg * 8];
                s16x8 bf = *(const s16x8*)&woT[(n0 + lr) * 64 + k0 + lg * 8];
                acc = __builtin_amdgcn_mfma_f32_16x16x32_bf16(af, bf, acc, 0, 0, 0);
            }
            const int col = n0 + lr;
            const float bias = bo[col];
            #pragma unroll
            for (int r = 0; r < 4; ++r) {
                int row = m0 + lg * 4 + r;
                if (row < S_)
                    t1[row * LDH + col] = acc[r] + bias + hf[row * LDH + col];
            }
        }
    }
    __syncthreads();

    // ---- 5. LN1: t1 -> h2 (hf f32 + hb bf16) ---------------------------
    {
        const int wv = t >> 6, d = t & 63;
        const float g = ln1g[d], bb = ln1b[d];
        for (int i = 0; i < 6; ++i) {
            int r = wv + 8 * i;
            if (r < S_) {
                float v = t1[r * LDH + d];
                float s = v, s2 = v * v;
                #pragma unroll
                for (int off = 32; off; off >>= 1) {
                    s  += __shfl_xor(s, off);
                    s2 += __shfl_xor(s2, off);
                }
                float mean = s * (1.0f / 64.0f);
                float var  = s2 * (1.0f / 64.0f) - mean * mean;
                float nv = (v - mean) * rsqrtf(var + 1e-5f);
                float res = nv * g + bb;
                hf[r * LDH + d] = res;
                hb[r * HBS + d] = f2bf(res);
            }
        }
    }
    __syncthreads();

    // ---- 6+7. FFN in two 128-col halves; FFN2 accumulates in regs ------
    f32x4 facc0 = {0.f, 0.f, 0.f, 0.f};
    f32x4 facc1 = {0.f, 0.f, 0.f, 0.f};
    for (int hx = 0; hx < 2; ++hx) {
        // FFN1 half: f = relu(h2 @ W1[:, hx*128..] + b1) -> fb
        for (int id = w; id < 24; id += 8) {
            const int m0 = (id % 3) << 4, nl = (id / 3) << 4;
            f32x4 acc = {0.f, 0.f, 0.f, 0.f};
            #pragma unroll
            for (int k0 = 0; k0 < 64; k0 += 32) {
                s16x8 af = *(const s16x8*)&hb[(m0 + lr) * HBS + k0 + lg * 8];
                s16x8 bf = *(const s16x8*)&w1T[(hx * 128 + nl + lr) * 64 + k0 + lg * 8];
                acc = __builtin_amdgcn_mfma_f32_16x16x32_bf16(af, bf, acc, 0, 0, 0);
            }
            const float bias = b1[hx * 128 + nl + lr];
            #pragma unroll
            for (int r = 0; r < 4; ++r) {
                int row = m0 + lg * 4 + r;
                if (row < S_)
                    fb[row * FBH + nl + lr] = f2bf(fmaxf(acc[r] + bias, 0.f));
            }
        }
        __syncthreads();
        // FFN2 partial: facc += f @ W2T[:, hx*128..]
        {
            const int m0 = (w % 3) << 4, n0 = (w / 3) << 4;
            #pragma unroll
            for (int k0 = 0; k0 < 128; k0 += 32) {
                s16x8 af = *(const s16x8*)&fb[(m0 + lr) * FBH + k0 + lg * 8];
                s16x8 bf = *(const s16x8*)&w2T[(n0 + lr) * 256 + hx * 128 + k0 + lg * 8];
                facc0 = __builtin_amdgcn_mfma_f32_16x16x32_bf16(af, bf, facc0, 0, 0, 0);
            }
        }
        if (w < 4) {
            const int id = w + 8;
            const int m0 = (id % 3) << 4, n0 = (id / 3) << 4;
            #pragma unroll
            for (int k0 = 0; k0 < 128; k0 += 32) {
                s16x8 af = *(const s16x8*)&fb[(m0 + lr) * FBH + k0 + lg * 8];
                s16x8 bf = *(const s16x8*)&w2T[(n0 + lr) * 256 + hx * 128 + k0 + lg * 8];
                facc1 = __builtin_amdgcn_mfma_f32_16x16x32_bf16(af, bf, facc1, 0, 0, 0);
            }
        }
        __syncthreads();   // before next half overwrites fb
    }
    // FFN2 epilogue: t2 = facc + b2 + h2 -> hf (in place)
    {
        const int m0 = (w % 3) << 4, n0 = (w / 3) << 4;
        const int col = n0 + lr;
        const float bias = b2[col];
        #pragma unroll
        for (int r = 0; r < 4; ++r) {
            int row = m0 + lg * 4 + r;
            if (row < S_) {
                int o = row * LDH + col;
                hf[o] = facc0[r] + bias + hf[o];
            }
        }
        if (w < 4) {
            const int id = w + 8;
            const int m1 = (id % 3) << 4, n1 = (id / 3) << 4;
            const int col1 = n1 + lr;
            const float bias1 = b2[col1];
            #pragma unroll
            for (int r = 0; r < 4; ++r) {
                int row = m1 + lg * 4 + r;
                if (row < S_) {
                    int o = row * LDH + col1;
                    hf[o] = facc1[r] + bias1 + hf[o];
                }
            }
        }
    }
    __syncthreads();

    // ---- 8. LN2: hf -> out ---------------------------------------------
    {
        const int wv = t >> 6, d = t & 63;
        const float g = ln2g[d], bb = ln2b[d];
        for (int i = 0; i < 6; ++i) {
            int r = wv + 8 * i;
            if (r < S_) {
                float v = hf[r * LDH + d];
                float s = v, s2 = v * v;
                #pragma unroll
                for (int off = 32; off; off >>= 1) {
                    s  += __shfl_xor(s, off);
                    s2 += __shfl_xor(s2, off);
                }
                float mean = s * (1.0f / 64.0f);
                float var  = s2 * (1.0f / 64.0f) - mean * mean;
                float nv = (v - mean) * rsqrtf(var + 1e-5f);
                out[(size_t)b * (S_ * D_) + r * 64 + d] = nv * g + bb;
            }
        }
    }
}

extern "C" void kernel_launch(void* const* d_in, const int* in_sizes, int n_in,
                              void* d_out, int out_size, void* d_ws, size_t ws_size,
                              hipStream_t stream) {
    const float* x    = (const float*)d_in[0];
    const float* Wq   = (const float*)d_in[1];
    const float* bq   = (const float*)d_in[2];
    const float* Wk   = (const float*)d_in[3];
    const float* bk   = (const float*)d_in[4];
    const float* Wv   = (const float*)d_in[5];
    const float* bv   = (const float*)d_in[6];
    const float* Wo   = (const float*)d_in[7];
    const float* bo   = (const float*)d_in[8];
    const float* ln1g = (const float*)d_in[9];
    const float* ln1b = (const float*)d_in[10];
    const float* W1   = (const float*)d_in[11];
    const float* b1   = (const float*)d_in[12];
    const float* W2   = (const float*)d_in[13];
    const float* b2   = (const float*)d_in[14];
    const float* ln2g = (const float*)d_in[15];
    const float* ln2b = (const float*)d_in[16];
    float* out = (float*)d_out;

    hipLaunchKernelGGL(prep_kernel, dim3(64), dim3(256), 0, stream,
                       Wq, Wk, Wv, Wo, W1, W2, d_ws);
    hipLaunchKernelGGL(encoder_kernel, dim3(NB), dim3(512), 0, stream,
                       x, bq, bk, bv, bo, ln1g, ln1b, b1, b2, ln2g, ln2b,
                       d_ws, out);
}

// Round 13
// 365.903 us; speedup vs baseline: 1.2137x; 1.1559x over previous
//
#include <hip/hip_runtime.h>
#include <math.h>

#define NB 8192
#define S_ 45
#define D_ 64
#define FF_ 256
#define LDH 68     // f32 row stride t1/t2
#define HBS 72     // bf16 row stride hb/ob (144 B)
#define KVS 68     // f32 row stride kf/vf
#define FBH 136    // bf16 row stride FFN half tile [48][136]

typedef __attribute__((ext_vector_type(4))) float f32x4;
typedef __attribute__((ext_vector_type(8))) short s16x8;
typedef __attribute__((ext_vector_type(4))) short s16x4;
typedef __fp16 h16x2 __attribute__((ext_vector_type(2)));

// ws layout (bytes): pe f32 [45*64] @0 ; WqkvT bf16 [192][64] @11520 ;
// WoT bf16 [64][64] @36096 ; W1T bf16 [256][64] @44288 ; W2T bf16 [64][256] @77056
#define WS_QKV 11520
#define WS_WO  36096
#define WS_W1  44288
#define WS_W2  77056

__device__ inline short f2bf(float f) {   // RNE float->bf16 bits
    union { float f; unsigned u; } c; c.f = f;
    unsigned u = c.u;
    return (short)((u + 0x7FFFu + ((u >> 16) & 1u)) >> 16);
}
__device__ inline float bf2f(short s) {
    union { unsigned u; float f; } c;
    c.u = ((unsigned)(unsigned short)s) << 16;
    return c.f;
}

__global__ void prep_kernel(const float* __restrict__ Wq, const float* __restrict__ Wk,
                            const float* __restrict__ Wv, const float* __restrict__ Wo,
                            const float* __restrict__ W1, const float* __restrict__ W2,
                            void* __restrict__ ws) {
    float* pe   = (float*)ws;
    short* wqkv = (short*)((char*)ws + WS_QKV);
    short* wo   = (short*)((char*)ws + WS_WO);
    short* w1   = (short*)((char*)ws + WS_W1);
    short* w2   = (short*)((char*)ws + WS_W2);
    int i = blockIdx.x * 256 + threadIdx.x;
    if (i < S_ * D_) {                       // positional encoding (f32)
        int s = i / D_, d = i % D_;
        float div = expf(-logf(10000.0f) * (float)(d & ~1) / (float)D_);
        float ang = (float)s * div;
        pe[i] = (d & 1) ? cosf(ang) : sinf(ang);
    }
    if (i < 12288) {                         // WqkvT[n][k] = W{q,k,v}[k][n&63]
        int n = i >> 6, k = i & 63;
        const float* W = (n < 64) ? Wq : (n < 128 ? Wk : Wv);
        wqkv[i] = f2bf(W[k * 64 + (n & 63)]);
    }
    if (i < 4096) {                          // WoT[n][k] = Wo[k][n]
        int n = i >> 6, k = i & 63;
        wo[i] = f2bf(Wo[k * 64 + n]);
    }
    if (i < 16384) {
        int n = i >> 6, k = i & 63;          // W1T[n][k] = W1[k][n]
        w1[i] = f2bf(W1[k * FF_ + n]);
        int n2 = i >> 8, k2 = i & 255;       // W2T[n][k] = W2[k][n]
        w2[i] = f2bf(W2[k2 * 64 + n2]);
    }
}

__launch_bounds__(512, 1)
__global__ void encoder_kernel(
    const float* __restrict__ x,
    const float* __restrict__ bq, const float* __restrict__ bk,
    const float* __restrict__ bv, const float* __restrict__ bo,
    const float* __restrict__ ln1g, const float* __restrict__ ln1b,
    const float* __restrict__ b1, const float* __restrict__ b2,
    const float* __restrict__ ln2g, const float* __restrict__ ln2b,
    const void* __restrict__ ws,
    float* __restrict__ out)
{
    const float* pe    = (const float*)ws;
    const short* wqkvT = (const short*)((const char*)ws + WS_QKV);
    const short* woT   = (const short*)((const char*)ws + WS_WO);
    const short* w1T   = (const short*)((const char*)ws + WS_W1);
    const short* w2T   = (const short*)((const char*)ws + WS_W2);

    // LDS pool 39168 B -> 4 blocks/CU. Overlays (phase-disjoint):
    //  @0     hb bf16 [48][72] 6912B  h (QKV A-op + residual1) -> h2 (LN1 out,
    //                                 FFN1 A-op + residual2). bf16-only residual.
    //  @6912  qh f16 [48][64] 6144B   q' scaled (cvt once per thread, outside loop)
    //  @13056 kf f32 [48][68] 13056B  k (f32: zero-cvt attention loop)
    //  @26112 vf f32 [48][68] 13056B  v (f32)
    //  overlays after attention (all reads fenced by a uniform barrier):
    //   ob bf16 [48][72] @6912 ; t1/t2 f32 [45][68] @16384 ; fb bf16 [48][136] @16384
    __shared__ __align__(16) char pool[39168];
    short*   hb = (short*)pool;
    __fp16*  qh = (__fp16*)(pool + 6912);
    float*   kf = (float*)(pool + 13056);
    float*   vf = (float*)(pool + 26112);
    short*   ob = (short*)(pool + 6912);
    float*   t1 = (float*)(pool + 16384);
    short*   fb = (short*)(pool + 16384);
    float*   t2 = (float*)(pool + 16384);

    const int t = threadIdx.x;
    const int b = blockIdx.x;
    const int w = t >> 6, l = t & 63;
    const int lr = l & 15, lg = l >> 4;   // MFMA frag coords

    // ---- 1. h = x + pe -> hb (bf16); zero pad rows ---------------------
    {
        const float4* x4 = (const float4*)(x + (size_t)b * (S_ * D_));
        const float4* p4 = (const float4*)pe;
        for (int i = t; i < S_ * D_ / 4; i += 512) {
            int r = i >> 4, c4 = (i & 15) << 2;
            float4 a = x4[i], p = p4[i];
            s16x4 hv16 = { f2bf(a.x + p.x), f2bf(a.y + p.y),
                           f2bf(a.z + p.z), f2bf(a.w + p.w) };
            *(s16x4*)&hb[r * HBS + c4] = hv16;
        }
        for (int i = t; i < 3 * HBS; i += 512) hb[45 * HBS + i] = 0;
    }
    __syncthreads();

    // ---- 2. fused QKV via MFMA -> qh (f16 scaled), kf (f32), vf (f32) --
    {
        const float SC2 = 0.35355339059327373f * 1.44269504088896340f; // 1/sqrt(8)*log2e
        for (int id = w; id < 36; id += 8) {
            const int m0 = (id % 3) << 4, n0 = (id / 3) << 4;
            f32x4 acc = {0.f, 0.f, 0.f, 0.f};
            #pragma unroll
            for (int k0 = 0; k0 < 64; k0 += 32) {
                s16x8 af = *(const s16x8*)&hb[(m0 + lr) * HBS + k0 + lg * 8];
                s16x8 bf = *(const s16x8*)&wqkvT[(n0 + lr) * 64 + k0 + lg * 8];
                acc = __builtin_amdgcn_mfma_f32_16x16x32_bf16(af, bf, acc, 0, 0, 0);
            }
            if (n0 < 64) {                       // q' = (q+bq)*SC2, f16
                const float bias = bq[n0 + lr];
                #pragma unroll
                for (int r = 0; r < 4; ++r)
                    qh[(m0 + lg * 4 + r) * 64 + n0 + lr] = (__fp16)((acc[r] + bias) * SC2);
            } else if (n0 < 128) {               // k, f32
                const int cc = n0 - 64 + lr;
                const float bias = bk[cc];
                #pragma unroll
                for (int r = 0; r < 4; ++r)
                    kf[(m0 + lg * 4 + r) * KVS + cc] = acc[r] + bias;
            } else {                             // v, f32
                const int cc = n0 - 128 + lr;
                const float bias = bv[cc];
                #pragma unroll
                for (int r = 0; r < 4; ++r)
                    vf[(m0 + lg * 4 + r) * KVS + cc] = acc[r] + bias;
            }
        }
    }
    __syncthreads();

    // ---- 3. attention: R6-proven f32 loop; UNIFORM barriers ------------
    // (R12 bug: __syncthreads inside the t<360 divergence skewed wave 5's
    //  barrier count -> races. Compute under if, barrier for ALL, store
    //  under if — the R8-proven shape.)
    {
        const bool act = (t < S_ * 8);
        s16x8 o16;
        int qr = 0, hd = 0;
        if (act) {
            qr = t >> 3; hd = (t & 7) << 3;
            float qv[8];
            {
                const h16x2* qp = (const h16x2*)&qh[qr * 64 + hd];
                #pragma unroll
                for (int j = 0; j < 4; ++j) {
                    h16x2 qq = qp[j];
                    qv[2 * j]     = (float)qq.x;
                    qv[2 * j + 1] = (float)qq.y;
                }
            }
            float o[8];
            #pragma unroll
            for (int j = 0; j < 8; ++j) o[j] = 0.f;
            float lsum = 0.f;
            #pragma unroll 3
            for (int k = 0; k < S_; ++k) {
                float4 k1 = *(const float4*)&kf[k * KVS + hd];
                float4 k2 = *(const float4*)&kf[k * KVS + hd + 4];
                float d = qv[0] * k1.x + qv[1] * k1.y + qv[2] * k1.z + qv[3] * k1.w +
                          qv[4] * k2.x + qv[5] * k2.y + qv[6] * k2.z + qv[7] * k2.w;
                float p = __builtin_amdgcn_exp2f(d);   // scale folded into q'
                lsum += p;
                float4 v1 = *(const float4*)&vf[k * KVS + hd];
                float4 v2 = *(const float4*)&vf[k * KVS + hd + 4];
                o[0] += p * v1.x; o[1] += p * v1.y; o[2] += p * v1.z; o[3] += p * v1.w;
                o[4] += p * v2.x; o[5] += p * v2.y; o[6] += p * v2.z; o[7] += p * v2.w;
            }
            float inv = 1.0f / lsum;
            #pragma unroll
            for (int j = 0; j < 8; ++j) o16[j] = f2bf(o[j] * inv);
        }
        __syncthreads();     // ALL threads: qh/kf/vf reads done before ob overlay
        if (act)
            *(s16x8*)&ob[qr * HBS + hd] = o16;
    }
    __syncthreads();

    // ---- 4. t1 = o @ Wo + bo + h (residual from hb), MFMA -> t1 (f32) --
    {
        for (int id = w; id < 12; id += 8) {
            const int m0 = (id % 3) << 4, n0 = (id / 3) << 4;
            f32x4 acc = {0.f, 0.f, 0.f, 0.f};
            #pragma unroll
            for (int k0 = 0; k0 < 64; k0 += 32) {
                s16x8 af = *(const s16x8*)&ob[(m0 + lr) * HBS + k0 + lg * 8];
                s16x8 bf = *(const s16x8*)&woT[(n0 + lr) * 64 + k0 + lg * 8];
                acc = __builtin_amdgcn_mfma_f32_16x16x32_bf16(af, bf, acc, 0, 0, 0);
            }
            const int col = n0 + lr;
            const float bias = bo[col];
            #pragma unroll
            for (int r = 0; r < 4; ++r) {
                int row = m0 + lg * 4 + r;
                if (row < S_)
                    t1[row * LDH + col] = acc[r] + bias + bf2f(hb[row * HBS + col]);
            }
        }
    }
    __syncthreads();

    // ---- 5. LN1: t1 -> h2 (hb bf16; pad rows stay zero) ----------------
    {
        const int wv = t >> 6, d = t & 63;
        const float g = ln1g[d], bb = ln1b[d];
        for (int i = 0; i < 6; ++i) {
            int r = wv + 8 * i;
            if (r < S_) {
                float v = t1[r * LDH + d];
                float s = v, s2 = v * v;
                #pragma unroll
                for (int off = 32; off; off >>= 1) {
                    s  += __shfl_xor(s, off);
                    s2 += __shfl_xor(s2, off);
                }
                float mean = s * (1.0f / 64.0f);
                float var  = s2 * (1.0f / 64.0f) - mean * mean;
                float nv = (v - mean) * rsqrtf(var + 1e-5f);
                hb[r * HBS + d] = f2bf(nv * g + bb);
            }
        }
    }
    __syncthreads();

    // ---- 6+7. FFN in two 128-col halves; FFN2 accumulates in regs ------
    f32x4 facc0 = {0.f, 0.f, 0.f, 0.f};
    f32x4 facc1 = {0.f, 0.f, 0.f, 0.f};
    for (int hx = 0; hx < 2; ++hx) {
        // FFN1 half: f = relu(h2 @ W1[:, hx*128..] + b1) -> fb
        for (int id = w; id < 24; id += 8) {
            const int m0 = (id % 3) << 4, nl = (id / 3) << 4;
            f32x4 acc = {0.f, 0.f, 0.f, 0.f};
            #pragma unroll
            for (int k0 = 0; k0 < 64; k0 += 32) {
                s16x8 af = *(const s16x8*)&hb[(m0 + lr) * HBS + k0 + lg * 8];
                s16x8 bf = *(const s16x8*)&w1T[(hx * 128 + nl + lr) * 64 + k0 + lg * 8];
                acc = __builtin_amdgcn_mfma_f32_16x16x32_bf16(af, bf, acc, 0, 0, 0);
            }
            const float bias = b1[hx * 128 + nl + lr];
            #pragma unroll
            for (int r = 0; r < 4; ++r) {
                int row = m0 + lg * 4 + r;
                if (row < S_)
                    fb[row * FBH + nl + lr] = f2bf(fmaxf(acc[r] + bias, 0.f));
            }
        }
        __syncthreads();
        // FFN2 partial: facc += f @ W2T[:, hx*128..]
        {
            const int m0 = (w % 3) << 4, n0 = (w / 3) << 4;
            #pragma unroll
            for (int k0 = 0; k0 < 128; k0 += 32) {
                s16x8 af = *(const s16x8*)&fb[(m0 + lr) * FBH + k0 + lg * 8];
                s16x8 bf = *(const s16x8*)&w2T[(n0 + lr) * 256 + hx * 128 + k0 + lg * 8];
                facc0 = __builtin_amdgcn_mfma_f32_16x16x32_bf16(af, bf, facc0, 0, 0, 0);
            }
        }
        if (w < 4) {
            const int id = w + 8;
            const int m0 = (id % 3) << 4, n0 = (id / 3) << 4;
            #pragma unroll
            for (int k0 = 0; k0 < 128; k0 += 32) {
                s16x8 af = *(const s16x8*)&fb[(m0 + lr) * FBH + k0 + lg * 8];
                s16x8 bf = *(const s16x8*)&w2T[(n0 + lr) * 256 + hx * 128 + k0 + lg * 8];
                facc1 = __builtin_amdgcn_mfma_f32_16x16x32_bf16(af, bf, facc1, 0, 0, 0);
            }
        }
        __syncthreads();   // before next half overwrites fb
    }
    // FFN2 epilogue: t2 = facc + b2 + h2 (residual from hb) -> t2 (f32)
    {
        const int m0 = (w % 3) << 4, n0 = (w / 3) << 4;
        const int col = n0 + lr;
        const float bias = b2[col];
        #pragma unroll
        for (int r = 0; r < 4; ++r) {
            int row = m0 + lg * 4 + r;
            if (row < S_)
                t2[row * LDH + col] = facc0[r] + bias + bf2f(hb[row * HBS + col]);
        }
        if (w < 4) {
            const int id = w + 8;
            const int m1 = (id % 3) << 4, n1 = (id / 3) << 4;
            const int col1 = n1 + lr;
            const float bias1 = b2[col1];
            #pragma unroll
            for (int r = 0; r < 4; ++r) {
                int row = m1 + lg * 4 + r;
                if (row < S_)
                    t2[row * LDH + col1] = facc1[r] + bias1 + bf2f(hb[row * HBS + col1]);
            }
        }
    }
    __syncthreads();

    // ---- 8. LN2: t2 -> out ---------------------------------------------
    {
        const int wv = t >> 6, d = t & 63;
        const float g = ln2g[d], bb = ln2b[d];
        for (int i = 0; i < 6; ++i) {
            int r = wv + 8 * i;
            if (r < S_) {
                float v = t2[r * LDH + d];
                float s = v, s2 = v * v;
                #pragma unroll
                for (int off = 32; off; off >>= 1) {
                    s  += __shfl_xor(s, off);
                    s2 += __shfl_xor(s2, off);
                }
                float mean = s * (1.0f / 64.0f);
                float var  = s2 * (1.0f / 64.0f) - mean * mean;
                float nv = (v - mean) * rsqrtf(var + 1e-5f);
                out[(size_t)b * (S_ * D_) + r * 64 + d] = nv * g + bb;
            }
        }
    }
}

extern "C" void kernel_launch(void* const* d_in, const int* in_sizes, int n_in,
                              void* d_out, int out_size, void* d_ws, size_t ws_size,
                              hipStream_t stream) {
    const float* x    = (const float*)d_in[0];
    const float* Wq   = (const float*)d_in[1];
    const float* bq   = (const float*)d_in[2];
    const float* Wk   = (const float*)d_in[3];
    const float* bk   = (const float*)d_in[4];
    const float* Wv   = (const float*)d_in[5];
    const float* bv   = (const float*)d_in[6];
    const float* Wo   = (const float*)d_in[7];
    const float* bo   = (const float*)d_in[8];
    const float* ln1g = (const float*)d_in[9];
    const float* ln1b = (const float*)d_in[10];
    const float* W1   = (const float*)d_in[11];
    const float* b1   = (const float*)d_in[12];
    const float* W2   = (const float*)d_in[13];
    const float* b2   = (const float*)d_in[14];
    const float* ln2g = (const float*)d_in[15];
    const float* ln2b = (const float*)d_in[16];
    float* out = (float*)d_out;

    hipLaunchKernelGGL(prep_kernel, dim3(64), dim3(256), 0, stream,
                       Wq, Wk, Wv, Wo, W1, W2, d_ws);
    hipLaunchKernelGGL(encoder_kernel, dim3(NB), dim3(512), 0, stream,
                       x, bq, bk, bv, bo, ln1g, ln1b, b1, b2, ln2g, ln2b,
                       d_ws, out);
}

// Round 14
// 321.460 us; speedup vs baseline: 1.3815x; 1.1383x over previous
//
#include <hip/hip_runtime.h>
#include <math.h>

#define NB 8192
#define S_ 45
#define D_ 64
#define FF_ 256
#define LDH 68     // f32 row stride t1/t2
#define HBS 72     // bf16 row stride hb/qb/kb/ob (144 B)
#define VTS 56     // bf16 row stride vT [72][56] (112 B, 16B-aligned)
#define FBH 136    // bf16 row stride FFN half tile [48][136]

typedef __attribute__((ext_vector_type(4))) float f32x4;
typedef __attribute__((ext_vector_type(8))) short s16x8;
typedef __attribute__((ext_vector_type(4))) short s16x4;

// ws layout (bytes): pe f32 [45*64] @0 ; WqkvT bf16 [192][64] @11520 ;
// WoT bf16 [64][64] @36096 ; W1T bf16 [256][64] @44288 ; W2T bf16 [64][256] @77056
#define WS_QKV 11520
#define WS_WO  36096
#define WS_W1  44288
#define WS_W2  77056

__device__ inline short f2bf(float f) {   // RNE float->bf16 bits
    union { float f; unsigned u; } c; c.f = f;
    unsigned u = c.u;
    return (short)((u + 0x7FFFu + ((u >> 16) & 1u)) >> 16);
}
__device__ inline float bf2f(short s) {
    union { unsigned u; float f; } c;
    c.u = ((unsigned)(unsigned short)s) << 16;
    return c.f;
}

__global__ void prep_kernel(const float* __restrict__ Wq, const float* __restrict__ Wk,
                            const float* __restrict__ Wv, const float* __restrict__ Wo,
                            const float* __restrict__ W1, const float* __restrict__ W2,
                            void* __restrict__ ws) {
    float* pe   = (float*)ws;
    short* wqkv = (short*)((char*)ws + WS_QKV);
    short* wo   = (short*)((char*)ws + WS_WO);
    short* w1   = (short*)((char*)ws + WS_W1);
    short* w2   = (short*)((char*)ws + WS_W2);
    int i = blockIdx.x * 256 + threadIdx.x;
    if (i < S_ * D_) {                       // positional encoding (f32)
        int s = i / D_, d = i % D_;
        float div = expf(-logf(10000.0f) * (float)(d & ~1) / (float)D_);
        float ang = (float)s * div;
        pe[i] = (d & 1) ? cosf(ang) : sinf(ang);
    }
    if (i < 12288) {                         // WqkvT[n][k] = W{q,k,v}[k][n&63]
        int n = i >> 6, k = i & 63;
        const float* W = (n < 64) ? Wq : (n < 128 ? Wk : Wv);
        wqkv[i] = f2bf(W[k * 64 + (n & 63)]);
    }
    if (i < 4096) {                          // WoT[n][k] = Wo[k][n]
        int n = i >> 6, k = i & 63;
        wo[i] = f2bf(Wo[k * 64 + n]);
    }
    if (i < 16384) {
        int n = i >> 6, k = i & 63;          // W1T[n][k] = W1[k][n]
        w1[i] = f2bf(W1[k * FF_ + n]);
        int n2 = i >> 8, k2 = i & 255;       // W2T[n][k] = W2[k][n]
        w2[i] = f2bf(W2[k2 * 64 + n2]);
    }
}

__launch_bounds__(512, 1)
__global__ void encoder_kernel(
    const float* __restrict__ x,
    const float* __restrict__ bq, const float* __restrict__ bk,
    const float* __restrict__ bv, const float* __restrict__ bo,
    const float* __restrict__ ln1g, const float* __restrict__ ln1b,
    const float* __restrict__ b1, const float* __restrict__ b2,
    const float* __restrict__ ln2g, const float* __restrict__ ln2b,
    const void* __restrict__ ws,
    float* __restrict__ out)
{
    const float* pe    = (const float*)ws;
    const short* wqkvT = (const short*)((const char*)ws + WS_QKV);
    const short* woT   = (const short*)((const char*)ws + WS_WO);
    const short* w1T   = (const short*)((const char*)ws + WS_W1);
    const short* w2T   = (const short*)((const char*)ws + WS_W2);

    // LDS pool 28800 B (not the occupancy limiter; waves cap at 4 blk/CU):
    //  @0     hb bf16 [48][72] 6912B  h (residual1) -> h2 (residual2)
    //  @6912  qb bf16 [48][72] 6912B  q' scaled    | ob (attn out) after barrier
    //  @13824 kb bf16 [48][72] 6912B  k            | t1/t2 f32, fb bf16 (FFN)
    //  @20736 vT bf16 [72][56] 8064B  v transposed [d][kr] (rows 64-71 = overread pad)
    __shared__ __align__(16) char pool[28800];
    short* hb = (short*)pool;
    short* qb = (short*)(pool + 6912);
    short* kb = (short*)(pool + 13824);
    short* vT = (short*)(pool + 20736);
    short* ob = qb;
    float* t1 = (float*)(pool + 13824);
    short* fb = (short*)(pool + 13824);
    float* t2 = (float*)(pool + 13824);

    const int t = threadIdx.x;
    const int b = blockIdx.x;
    const int w = t >> 6, l = t & 63;
    const int lr = l & 15, lg = l >> 4;   // MFMA frag coords
    const s16x8 zero8 = {0, 0, 0, 0, 0, 0, 0, 0};

    // ---- 1. h = x + pe -> hb (bf16); zero pad rows ---------------------
    {
        const float4* x4 = (const float4*)(x + (size_t)b * (S_ * D_));
        const float4* p4 = (const float4*)pe;
        for (int i = t; i < S_ * D_ / 4; i += 512) {
            int r = i >> 4, c4 = (i & 15) << 2;
            float4 a = x4[i], p = p4[i];
            s16x4 hv16 = { f2bf(a.x + p.x), f2bf(a.y + p.y),
                           f2bf(a.z + p.z), f2bf(a.w + p.w) };
            *(s16x4*)&hb[r * HBS + c4] = hv16;
        }
        for (int i = t; i < 3 * HBS; i += 512) hb[45 * HBS + i] = 0;
    }
    __syncthreads();

    // ---- 2. fused QKV via MFMA -> qb (bf16 scaled), kb (bf16), vT ------
    {
        const float SC2 = 0.35355339059327373f * 1.44269504088896340f; // 1/sqrt(8)*log2e
        for (int id = w; id < 36; id += 8) {
            const int m0 = (id % 3) << 4, n0 = (id / 3) << 4;
            f32x4 acc = {0.f, 0.f, 0.f, 0.f};
            #pragma unroll
            for (int k0 = 0; k0 < 64; k0 += 32) {
                s16x8 af = *(const s16x8*)&hb[(m0 + lr) * HBS + k0 + lg * 8];
                s16x8 bf = *(const s16x8*)&wqkvT[(n0 + lr) * 64 + k0 + lg * 8];
                acc = __builtin_amdgcn_mfma_f32_16x16x32_bf16(af, bf, acc, 0, 0, 0);
            }
            if (n0 < 64) {                       // q' = (q+bq)*SC2
                const float bias = bq[n0 + lr];
                #pragma unroll
                for (int r = 0; r < 4; ++r)
                    qb[(m0 + lg * 4 + r) * HBS + n0 + lr] = f2bf((acc[r] + bias) * SC2);
            } else if (n0 < 128) {               // k
                const int cc = n0 - 64 + lr;
                const float bias = bk[cc];
                #pragma unroll
                for (int r = 0; r < 4; ++r)
                    kb[(m0 + lg * 4 + r) * HBS + cc] = f2bf(acc[r] + bias);
            } else {                             // v -> vT[d][kr] (K-axis pads
                const int cc = n0 - 128 + lr;    //  finite; P masks kr>=45)
                const float bias = bv[cc];
                s16x4 vv = { f2bf(acc[0] + bias), f2bf(acc[1] + bias),
                             f2bf(acc[2] + bias), f2bf(acc[3] + bias) };
                *(s16x4*)&vT[cc * VTS + m0 + lg * 4] = vv;
            }
        }
    }
    __syncthreads();

    // ---- 3. attention: swapped QK^T (S^T=K.Q^T) + in-register softmax --
    // Lane (lr,lg) after mfma: S^T[kr=tm*16+lg*4+r][q=tn*16+lr] -> q is
    // lane-local; row-sum = in-lane 12 + 2 shfl_xor(lg axis). P repacked to
    // PV A-frags by 12 shfl/tn. One head per wave. All 512 threads uniform.
    {
        const int hd = w << 3;
        s16x8 pv_b0 = *(const s16x8*)&vT[(hd + lr) * VTS + lg * 8];          // kr 0-31
        s16x8 pv_b1 = (lg < 2) ? *(const s16x8*)&vT[(hd + lr) * VTS + 32 + lg * 8]
                               : zero8;                                      // kr 32-47
        f32x4 O[3];
        #pragma unroll
        for (int tn = 0; tn < 3; ++tn) {
            s16x8 qbf = (lg == 0) ? *(const s16x8*)&qb[(tn * 16 + lr) * HBS + hd] : zero8;
            f32x4 S[3];
            #pragma unroll
            for (int tm = 0; tm < 3; ++tm) {
                s16x8 kaf = (lg == 0) ? *(const s16x8*)&kb[(tm * 16 + lr) * HBS + hd] : zero8;
                f32x4 z = {0.f, 0.f, 0.f, 0.f};
                S[tm] = __builtin_amdgcn_mfma_f32_16x16x32_bf16(kaf, qbf, z, 0, 0, 0);
            }
            float psum = 0.f;
            #pragma unroll
            for (int tm = 0; tm < 3; ++tm) {
                #pragma unroll
                for (int r = 0; r < 4; ++r) {
                    float e = __builtin_amdgcn_exp2f(S[tm][r]);
                    if (tm == 2) e = (lg * 4 + r >= 13) ? 0.f : e;  // kr>=45 mask
                    S[tm][r] = e;
                    psum += e;
                }
            }
            float s = psum;
            s += __shfl_xor(s, 16);
            s += __shfl_xor(s, 32);
            float inv = 1.0f / s;
            unsigned pk0[3], pk1[3];   // bf16x2 packed P (truncation), per tm
            #pragma unroll
            for (int tm = 0; tm < 3; ++tm) {
                float a0 = S[tm][0] * inv, a1 = S[tm][1] * inv;
                float a2 = S[tm][2] * inv, a3 = S[tm][3] * inv;
                pk0[tm] = (__float_as_uint(a0) >> 16) | (__float_as_uint(a1) & 0xFFFF0000u);
                pk1[tm] = (__float_as_uint(a2) >> 16) | (__float_as_uint(a3) & 0xFFFF0000u);
            }
            // repack: lane (lr,lg') A-frag kr=lg'*8+j from lanes (lr, 2(lg'&1)) & +16
            const int srcA = lr + ((lg & 1) << 5);
            const int srcB = srcA + 16;
            unsigned gA0[3], gA1[3], gB0[3], gB1[3];
            #pragma unroll
            for (int tm = 0; tm < 3; ++tm) {
                gA0[tm] = (unsigned)__shfl((int)pk0[tm], srcA);
                gA1[tm] = (unsigned)__shfl((int)pk1[tm], srcA);
                gB0[tm] = (unsigned)__shfl((int)pk0[tm], srcB);
                gB1[tm] = (unsigned)__shfl((int)pk1[tm], srcB);
            }
            const bool tm1 = (lg >> 1) != 0;
            union { unsigned u[4]; s16x8 v; } a1c, a2c;
            a1c.u[0] = tm1 ? gA0[1] : gA0[0];
            a1c.u[1] = tm1 ? gA1[1] : gA1[0];
            a1c.u[2] = tm1 ? gB0[1] : gB0[0];
            a1c.u[3] = tm1 ? gB1[1] : gB1[0];
            const bool lo = (lg < 2);
            a2c.u[0] = lo ? gA0[2] : 0u;
            a2c.u[1] = lo ? gA1[2] : 0u;
            a2c.u[2] = lo ? gB0[2] : 0u;
            a2c.u[3] = lo ? gB1[2] : 0u;
            f32x4 z = {0.f, 0.f, 0.f, 0.f};
            O[tn] = __builtin_amdgcn_mfma_f32_16x16x32_bf16(a1c.v, pv_b0, z, 0, 0, 0);
            O[tn] = __builtin_amdgcn_mfma_f32_16x16x32_bf16(a2c.v, pv_b1, O[tn], 0, 0, 0);
        }
        __syncthreads();               // all qb/kb/vT reads done before ob overlay
        if (lr < 8) {
            #pragma unroll
            for (int tn = 0; tn < 3; ++tn)
                #pragma unroll
                for (int r = 0; r < 4; ++r) {
                    int row = tn * 16 + lg * 4 + r;
                    if (row < S_) ob[row * HBS + hd + lr] = f2bf(O[tn][r]);
                }
        }
    }
    __syncthreads();

    // ---- 4. t1 = o @ Wo + bo + h (residual from hb), MFMA -> t1 (f32) --
    {
        for (int id = w; id < 12; id += 8) {
            const int m0 = (id % 3) << 4, n0 = (id / 3) << 4;
            f32x4 acc = {0.f, 0.f, 0.f, 0.f};
            #pragma unroll
            for (int k0 = 0; k0 < 64; k0 += 32) {
                s16x8 af = *(const s16x8*)&ob[(m0 + lr) * HBS + k0 + lg * 8];
                s16x8 bf = *(const s16x8*)&woT[(n0 + lr) * 64 + k0 + lg * 8];
                acc = __builtin_amdgcn_mfma_f32_16x16x32_bf16(af, bf, acc, 0, 0, 0);
            }
            const int col = n0 + lr;
            const float bias = bo[col];
            #pragma unroll
            for (int r = 0; r < 4; ++r) {
                int row = m0 + lg * 4 + r;
                if (row < S_)
                    t1[row * LDH + col] = acc[r] + bias + bf2f(hb[row * HBS + col]);
            }
        }
    }
    __syncthreads();

    // ---- 5. LN1: t1 -> h2 (hb bf16; pad rows stay zero) ----------------
    {
        const int wv = t >> 6, d = t & 63;
        const float g = ln1g[d], bb = ln1b[d];
        for (int i = 0; i < 6; ++i) {
            int r = wv + 8 * i;
            if (r < S_) {
                float v = t1[r * LDH + d];
                float s = v, s2 = v * v;
                #pragma unroll
                for (int off = 32; off; off >>= 1) {
                    s  += __shfl_xor(s, off);
                    s2 += __shfl_xor(s2, off);
                }
                float mean = s * (1.0f / 64.0f);
                float var  = s2 * (1.0f / 64.0f) - mean * mean;
                float nv = (v - mean) * rsqrtf(var + 1e-5f);
                hb[r * HBS + d] = f2bf(nv * g + bb);
            }
        }
    }
    __syncthreads();

    // ---- 6+7. FFN in two 128-col halves; FFN2 accumulates in regs ------
    f32x4 facc0 = {0.f, 0.f, 0.f, 0.f};
    f32x4 facc1 = {0.f, 0.f, 0.f, 0.f};
    for (int hx = 0; hx < 2; ++hx) {
        for (int id = w; id < 24; id += 8) {
            const int m0 = (id % 3) << 4, nl = (id / 3) << 4;
            f32x4 acc = {0.f, 0.f, 0.f, 0.f};
            #pragma unroll
            for (int k0 = 0; k0 < 64; k0 += 32) {
                s16x8 af = *(const s16x8*)&hb[(m0 + lr) * HBS + k0 + lg * 8];
                s16x8 bf = *(const s16x8*)&w1T[(hx * 128 + nl + lr) * 64 + k0 + lg * 8];
                acc = __builtin_amdgcn_mfma_f32_16x16x32_bf16(af, bf, acc, 0, 0, 0);
            }
            const float bias = b1[hx * 128 + nl + lr];
            #pragma unroll
            for (int r = 0; r < 4; ++r) {
                int row = m0 + lg * 4 + r;
                if (row < S_)
                    fb[row * FBH + nl + lr] = f2bf(fmaxf(acc[r] + bias, 0.f));
            }
        }
        __syncthreads();
        {
            const int m0 = (w % 3) << 4, n0 = (w / 3) << 4;
            #pragma unroll
            for (int k0 = 0; k0 < 128; k0 += 32) {
                s16x8 af = *(const s16x8*)&fb[(m0 + lr) * FBH + k0 + lg * 8];
                s16x8 bf = *(const s16x8*)&w2T[(n0 + lr) * 256 + hx * 128 + k0 + lg * 8];
                facc0 = __builtin_amdgcn_mfma_f32_16x16x32_bf16(af, bf, facc0, 0, 0, 0);
            }
        }
        if (w < 4) {
            const int id = w + 8;
            const int m0 = (id % 3) << 4, n0 = (id / 3) << 4;
            #pragma unroll
            for (int k0 = 0; k0 < 128; k0 += 32) {
                s16x8 af = *(const s16x8*)&fb[(m0 + lr) * FBH + k0 + lg * 8];
                s16x8 bf = *(const s16x8*)&w2T[(n0 + lr) * 256 + hx * 128 + k0 + lg * 8];
                facc1 = __builtin_amdgcn_mfma_f32_16x16x32_bf16(af, bf, facc1, 0, 0, 0);
            }
        }
        __syncthreads();   // before next half overwrites fb
    }
    // FFN2 epilogue: t2 = facc + b2 + h2 (residual from hb) -> t2 (f32)
    {
        const int m0 = (w % 3) << 4, n0 = (w / 3) << 4;
        const int col = n0 + lr;
        const float bias = b2[col];
        #pragma unroll
        for (int r = 0; r < 4; ++r) {
            int row = m0 + lg * 4 + r;
            if (row < S_)
                t2[row * LDH + col] = facc0[r] + bias + bf2f(hb[row * HBS + col]);
        }
        if (w < 4) {
            const int id = w + 8;
            const int m1 = (id % 3) << 4, n1 = (id / 3) << 4;
            const int col1 = n1 + lr;
            const float bias1 = b2[col1];
            #pragma unroll
            for (int r = 0; r < 4; ++r) {
                int row = m1 + lg * 4 + r;
                if (row < S_)
                    t2[row * LDH + col1] = facc1[r] + bias1 + bf2f(hb[row * HBS + col1]);
            }
        }
    }
    __syncthreads();

    // ---- 8. LN2: t2 -> out ---------------------------------------------
    {
        const int wv = t >> 6, d = t & 63;
        const float g = ln2g[d], bb = ln2b[d];
        for (int i = 0; i < 6; ++i) {
            int r = wv + 8 * i;
            if (r < S_) {
                float v = t2[r * LDH + d];
                float s = v, s2 = v * v;
                #pragma unroll
                for (int off = 32; off; off >>= 1) {
                    s  += __shfl_xor(s, off);
                    s2 += __shfl_xor(s2, off);
                }
                float mean = s * (1.0f / 64.0f);
                float var  = s2 * (1.0f / 64.0f) - mean * mean;
                float nv = (v - mean) * rsqrtf(var + 1e-5f);
                out[(size_t)b * (S_ * D_) + r * 64 + d] = nv * g + bb;
            }
        }
    }
}

extern "C" void kernel_launch(void* const* d_in, const int* in_sizes, int n_in,
                              void* d_out, int out_size, void* d_ws, size_t ws_size,
                              hipStream_t stream) {
    const float* x    = (const float*)d_in[0];
    const float* Wq   = (const float*)d_in[1];
    const float* bq   = (const float*)d_in[2];
    const float* Wk   = (const float*)d_in[3];
    const float* bk   = (const float*)d_in[4];
    const float* Wv   = (const float*)d_in[5];
    const float* bv   = (const float*)d_in[6];
    const float* Wo   = (const float*)d_in[7];
    const float* bo   = (const float*)d_in[8];
    const float* ln1g = (const float*)d_in[9];
    const float* ln1b = (const float*)d_in[10];
    const float* W1   = (const float*)d_in[11];
    const float* b1   = (const float*)d_in[12];
    const float* W2   = (const float*)d_in[13];
    const float* b2   = (const float*)d_in[14];
    const float* ln2g = (const float*)d_in[15];
    const float* ln2b = (const float*)d_in[16];
    float* out = (float*)d_out;

    hipLaunchKernelGGL(prep_kernel, dim3(64), dim3(256), 0, stream,
                       Wq, Wk, Wv, Wo, W1, W2, d_ws);
    hipLaunchKernelGGL(encoder_kernel, dim3(NB), dim3(512), 0, stream,
                       x, bq, bk, bv, bo, ln1g, ln1b, b1, b2, ln2g, ln2b,
                       d_ws, out);
}